// Round 4
// baseline (1738.194 us; speedup 1.0000x reference)
//
#include <hip/hip_runtime.h>

__global__ void k_fill(unsigned* p, int n, unsigned v) {
    int i = blockIdx.x * blockDim.x + threadIdx.x;
    if (i < n) p[i] = v;
}

// ---------------- CSR build (graph identical across layers; built once) ----------------
__global__ void k_hist(const int* __restrict__ ei, int E, int* __restrict__ deg) {
    int e = blockIdx.x * blockDim.x + threadIdx.x;
    if (e < E) atomicAdd(&deg[ei[E + e]], 1);
}

__global__ void k_scan_blocks(const int* __restrict__ deg, int N,
                              int* __restrict__ excl, int* __restrict__ parts) {
    __shared__ int s[256];
    int t = threadIdx.x, i = blockIdx.x * 256 + t;
    int v = (i < N) ? deg[i] : 0;
    s[t] = v;
    __syncthreads();
    int acc = v;
    for (int off = 1; off < 256; off <<= 1) {
        int add = (t >= off) ? s[t - off] : 0;
        __syncthreads();
        acc += add;
        s[t] = acc;
        __syncthreads();
    }
    if (i < N) excl[i] = acc - v;
    if (t == 255) parts[blockIdx.x] = acc;
}

__global__ void k_scan_parts(int* __restrict__ parts, int nb) {
    __shared__ int s[256];
    int t = threadIdx.x;
    int v = (t < nb) ? parts[t] : 0;
    s[t] = v;
    __syncthreads();
    int acc = v;
    for (int off = 1; off < 256; off <<= 1) {
        int add = (t >= off) ? s[t - off] : 0;
        __syncthreads();
        acc += add;
        s[t] = acc;
        __syncthreads();
    }
    if (t < nb) parts[t] = acc - v;
}

__global__ void k_scan_add(const int* __restrict__ excl, const int* __restrict__ parts,
                           int* __restrict__ row_ptr, int* __restrict__ cursor, int N) {
    int i = blockIdx.x * blockDim.x + threadIdx.x;
    if (i >= N) return;
    int r = excl[i] + parts[i >> 8];
    row_ptr[i] = r;
    cursor[i] = r;
}

__global__ void k_scatter(const int* __restrict__ ei, int E, int* __restrict__ cursor,
                          int* __restrict__ esrc, int* __restrict__ eeid) {
    int e = blockIdx.x * blockDim.x + threadIdx.x;
    if (e >= E) return;
    int d = ei[E + e];
    int j = atomicAdd(&cursor[d], 1);
    esrc[j] = ei[e];
    eeid[j] = e;
}

// fill edst[slot] = dst node (CSR ranges, one thread per node)
__global__ void k_dstfill(const int* __restrict__ row_ptr, const int* __restrict__ deg,
                          int* __restrict__ edst, int N) {
    int n = blockIdx.x * blockDim.x + threadIdx.x;
    if (n >= N) return;
    int s = row_ptr[n], d = deg[n];
    for (int i = 0; i < d; i++) edst[s + i] = n;
}

// ---------------- Dual GEMM: out{l,r} = A @ W{l,r} + b{l,r} ----------------
template <int M, int RW>
__global__ __launch_bounds__(256) void k_gemm2(const float* __restrict__ A,
                                               const float* __restrict__ Wl, const float* __restrict__ bl,
                                               const float* __restrict__ Wr, const float* __restrict__ br,
                                               float* __restrict__ outl, float* __restrict__ outr) {
    constexpr int TX = M / 4;
    __shared__ float sA[32][68];
    __shared__ float sW[32][M];
    const float* W    = blockIdx.y ? Wr : Wl;
    const float* bias = blockIdx.y ? br : bl;
    float* out        = blockIdx.y ? outr : outl;
    int t = threadIdx.x;
    int tx = t % TX, ty = t / TX;
    int r0 = blockIdx.x * 64;
    float acc[RW][4] = {};
    for (int kt = 0; kt < 128; kt += 32) {
        for (int l = t; l < 512; l += 256) {
            int row = l >> 3, kq = (l & 7) << 2;
            float4 a = *(const float4*)&A[(size_t)(r0 + row) * 128 + kt + kq];
            sA[kq + 0][row] = a.x; sA[kq + 1][row] = a.y;
            sA[kq + 2][row] = a.z; sA[kq + 3][row] = a.w;
        }
        for (int l = t; l < 32 * M / 4; l += 256) {
            int kk = (l * 4) / M, cc = (l * 4) % M;
            *(float4*)&sW[kk][cc] = *(const float4*)&W[(size_t)(kt + kk) * M + cc];
        }
        __syncthreads();
#pragma unroll
        for (int k = 0; k < 32; k++) {
            float4 w = *(float4*)&sW[k][tx * 4];
            float ar[RW];
#pragma unroll
            for (int i = 0; i < RW; i += 4) {
                float4 a = *(float4*)&sA[k][ty * RW + i];
                ar[i] = a.x; ar[i + 1] = a.y; ar[i + 2] = a.z; ar[i + 3] = a.w;
            }
#pragma unroll
            for (int i = 0; i < RW; i++) {
                acc[i][0] += ar[i] * w.x; acc[i][1] += ar[i] * w.y;
                acc[i][2] += ar[i] * w.z; acc[i][3] += ar[i] * w.w;
            }
        }
        __syncthreads();
    }
    float4 b = *(const float4*)&bias[tx * 4];
#pragma unroll
    for (int i = 0; i < RW; i++) {
        float4 v;
        v.x = acc[i][0] + b.x; v.y = acc[i][1] + b.y;
        v.z = acc[i][2] + b.z; v.w = acc[i][3] + b.w;
        *(float4*)&out[(size_t)(r0 + ty * RW + i) * M + tx * 4] = v;
    }
}

// ---------------- Edge logit kernel: per CSR slot s, per head h ----------------
// logit[s,h] = sum_c att[h,c] * leaky( xl[src,c] + xr[dst,c] + (ea[eid] @ We)[c] )
// GEMM on k_gemm2's transposed-LDS pattern (float4 LDS reads), 64 slots/block,
// epilogue gathers xl/xr as coalesced float4 and shuffle-reduces per 16-lane head group.
// Writes 4-8 B/edge instead of materializing the 512B ee row.
template <int HC>
__global__ __launch_bounds__(256) void k_elogit(const float* __restrict__ ea,
                                                const int* __restrict__ eeid,
                                                const int* __restrict__ esrc,
                                                const int* __restrict__ edst,
                                                const float* __restrict__ We,
                                                const float* __restrict__ att,
                                                const float* __restrict__ xl,
                                                const float* __restrict__ xr,
                                                float* __restrict__ logit, int E) {
    constexpr int ROWS = 64;
    constexpr int TX = HC / 4;            // 32 (HC=128) or 16 (HC=64)
    constexpr int RW = ROWS / (256 / TX); // 8 or 4
    __shared__ float sA[32][ROWS + 4];    // k-major: sA[k][row]
    __shared__ float sW[32][HC];
    int sb = blockIdx.x * ROWS;
    if (sb >= E) return;
    int t = threadIdx.x;
    for (int l = t; l < ROWS * 8; l += 256) {
        int row = l >> 3, kq = (l & 7) << 2;
        int s = sb + row;
        int eid = (s < E) ? eeid[s] : 0;
        float4 a = *(const float4*)&ea[(size_t)eid * 32 + kq];
        sA[kq + 0][row] = a.x; sA[kq + 1][row] = a.y;
        sA[kq + 2][row] = a.z; sA[kq + 3][row] = a.w;
    }
    for (int l = t; l < 32 * HC / 4; l += 256) {
        int k = (l * 4) / HC, c = (l * 4) % HC;
        *(float4*)&sW[k][c] = *(const float4*)&We[k * HC + c];
    }
    __syncthreads();
    int tx = t % TX, ty = t / TX;
    float4 attv = *(const float4*)&att[tx * 4];
    float acc[RW][4] = {};
#pragma unroll
    for (int k = 0; k < 32; k++) {
        float4 w = *(float4*)&sW[k][tx * 4];
        float ar[RW];
#pragma unroll
        for (int i = 0; i < RW; i += 4) {
            float4 a = *(float4*)&sA[k][ty * RW + i];
            ar[i] = a.x; ar[i + 1] = a.y; ar[i + 2] = a.z; ar[i + 3] = a.w;
        }
#pragma unroll
        for (int i = 0; i < RW; i++) {
            acc[i][0] = fmaf(ar[i], w.x, acc[i][0]);
            acc[i][1] = fmaf(ar[i], w.y, acc[i][1]);
            acc[i][2] = fmaf(ar[i], w.z, acc[i][2]);
            acc[i][3] = fmaf(ar[i], w.w, acc[i][3]);
        }
    }
#pragma unroll
    for (int i = 0; i < RW; i++) {
        int s = sb + ty * RW + i;
        bool ok = s < E;
        int src = ok ? esrc[s] : 0;
        int dst = ok ? edst[s] : 0;
        float4 xl4 = *(const float4*)&xl[(size_t)src * HC + tx * 4];
        float4 xr4 = *(const float4*)&xr[(size_t)dst * HC + tx * 4];
        float v0 = acc[i][0] + xl4.x + xr4.x; v0 = v0 > 0.f ? v0 : 0.2f * v0;
        float v1 = acc[i][1] + xl4.y + xr4.y; v1 = v1 > 0.f ? v1 : 0.2f * v1;
        float v2 = acc[i][2] + xl4.z + xr4.z; v2 = v2 > 0.f ? v2 : 0.2f * v2;
        float v3 = acc[i][3] + xl4.w + xr4.w; v3 = v3 > 0.f ? v3 : 0.2f * v3;
        float p = fmaf(attv.x, v0, fmaf(attv.y, v1, fmaf(attv.z, v2, attv.w * v3)));
#pragma unroll
        for (int m = 1; m < 16; m <<= 1) p += __shfl_xor(p, m);
        if constexpr (HC == 128) {
            if ((tx & 15) == 0 && ok) logit[2 * (size_t)s + (tx >> 4)] = p;
        } else {
            if (tx == 0 && ok) logit[s] = p;
        }
    }
}

// ---------------- Lean aggregation using precomputed logits ----------------
// Per visit: esrc (4B), logit (broadcast), xl float2 (coalesced 512B/wave), exp, 2 FMA.
// No shuffle butterfly, no We, no ea. Block = 4 waves = 2 nodes x 2 edge-parity waves.
// H==2: lane-half = head. H==1: lane-half = extra edge parity (4 edges in flight/wave-pair).
template <int H, bool RELU>
__global__ __launch_bounds__(256) void k_aggv(const float* __restrict__ xl,
                                              const float* __restrict__ logit,
                                              const int* __restrict__ esrc,
                                              const int* __restrict__ row_ptr, const int* __restrict__ deg,
                                              const float* __restrict__ bias,
                                              float* __restrict__ out, int N) {
    constexpr int HC = H * 64;
    __shared__ float2 sAcc[2][64];
    __shared__ float  sDen[2][64];
    int tid = threadIdx.x, wv = tid >> 6, lane = tid & 63;
    int ns = wv >> 1, eh = wv & 1;
    int n = blockIdx.x * 2 + ns;
    bool alive = n < N;
    int hf = lane >> 5, c2 = lane & 31;
    int col = (H == 2) ? (hf * 64 + 2 * c2) : (2 * c2);
    int start = 0, d = 0;
    if (alive) { start = row_ptr[n]; d = deg[n]; }
    float2 acc = make_float2(0.f, 0.f);
    float den = 0.f;
    const int jstep = (H == 2) ? 2 : 4;
    int jc = (H == 2) ? eh : (2 * eh + hf);

    bool okc = jc < d;
    int sC = start + jc, sN = sC + jstep;
    float lgC = 0.f;
    float2 xlC = make_float2(0.f, 0.f);
    if (okc) {
        lgC = (H == 2) ? logit[2 * (size_t)sC + hf] : logit[sC];
        xlC = *(const float2*)&xl[(size_t)esrc[sC] * HC + col];
    }
    bool okn = (jc + jstep) < d;
    while (okc) {
        float lgN = 0.f;
        float2 xlN = make_float2(0.f, 0.f);
        if (okn) {
            lgN = (H == 2) ? logit[2 * (size_t)sN + hf] : logit[sN];
            xlN = *(const float2*)&xl[(size_t)esrc[sN] * HC + col];
        }
        float ex = __expf(lgC);
        acc.x = fmaf(ex, xlC.x, acc.x);
        acc.y = fmaf(ex, xlC.y, acc.y);
        den += ex;
        jc += jstep; sC = sN; sN += jstep;
        lgC = lgN; xlC = xlN;
        okc = okn; okn = (jc + jstep) < d;
    }

    if constexpr (H == 1) {   // halves hold disjoint edge subsets of same channels
        acc.x += __shfl_xor(acc.x, 32);
        acc.y += __shfl_xor(acc.y, 32);
        den   += __shfl_xor(den, 32);
    }
    if (eh == 1) { sAcc[ns][lane] = acc; sDen[ns][lane] = den; }
    __syncthreads();
    if (eh == 0 && alive) {
        float2 a2 = sAcc[ns][lane];
        float dsum = den + sDen[ns][lane] + 1e-16f;
        float2 bv = *(const float2*)&bias[col];
        float o0 = (acc.x + a2.x) / dsum + bv.x;
        float o1 = (acc.y + a2.y) / dsum + bv.y;
        if (RELU) { o0 = fmaxf(o0, 0.f); o1 = fmaxf(o1, 0.f); }
        if (H == 2 || hf == 0)
            *(float2*)&out[(size_t)n * HC + col] = make_float2(o0, o1);
    }
}

// ---------------- Fallback agg (round-0 structure) — tiny-workspace path ----------------
template <int H, bool RELU>
__global__ __launch_bounds__(256) void k_agg_fb(const float* __restrict__ xl, const float* __restrict__ xr,
                                                const float* __restrict__ ea,
                                                const int* __restrict__ esrc, const int* __restrict__ eeid,
                                                const int* __restrict__ row_ptr, const int* __restrict__ deg,
                                                const float* __restrict__ We, const float* __restrict__ att,
                                                const float* __restrict__ bias, float* __restrict__ out, int N) {
    constexpr int HC = H * 64;
    int tid = threadIdx.x, wv = tid >> 6, lane = tid & 63;
    float rWe0[32], rWe1[H == 2 ? 32 : 1];
#pragma unroll
    for (int k = 0; k < 32; k++) rWe0[k] = We[k * HC + lane];
    if constexpr (H == 2) {
#pragma unroll
        for (int k = 0; k < 32; k++) rWe1[k] = We[k * HC + 64 + lane];
    }
    float att0 = att[lane], b0 = bias[lane];
    float att1 = 0.f, b1 = 0.f;
    if constexpr (H == 2) { att1 = att[64 + lane]; b1 = bias[64 + lane]; }
    int n = blockIdx.x * 4 + wv;
    if (n >= N) return;
    int start = row_ptr[n], d = deg[n];
    float xr0 = xr[(size_t)n * HC + lane];
    float xr1 = (H == 2) ? xr[(size_t)n * HC + 64 + lane] : 0.f;
    float acc0 = 0.f, acc1 = 0.f, den0 = 0.f, den1 = 0.f;
    for (int j = 0; j < d; j++) {
        int src = esrc[start + j], eid = eeid[start + j];
        const float4* eap = (const float4*)(ea + (size_t)eid * 32);
        const float* xls = xl + (size_t)src * HC;
        float xl0 = xls[lane];
        float xl1 = (H == 2) ? xls[64 + lane] : 0.f;
        float ee0 = 0.f, ee1 = 0.f;
#pragma unroll
        for (int kq = 0; kq < 8; kq++) {
            float4 v = eap[kq];
            ee0 = fmaf(v.x, rWe0[kq * 4 + 0], ee0);
            ee0 = fmaf(v.y, rWe0[kq * 4 + 1], ee0);
            ee0 = fmaf(v.z, rWe0[kq * 4 + 2], ee0);
            ee0 = fmaf(v.w, rWe0[kq * 4 + 3], ee0);
            if constexpr (H == 2) {
                ee1 = fmaf(v.x, rWe1[kq * 4 + 0], ee1);
                ee1 = fmaf(v.y, rWe1[kq * 4 + 1], ee1);
                ee1 = fmaf(v.z, rWe1[kq * 4 + 2], ee1);
                ee1 = fmaf(v.w, rWe1[kq * 4 + 3], ee1);
            }
        }
        float v0 = xl0 + xr0 + ee0;
        v0 = v0 > 0.f ? v0 : 0.2f * v0;
        float p0 = att0 * v0, p1 = 0.f;
        if constexpr (H == 2) {
            float v1 = xl1 + xr1 + ee1;
            v1 = v1 > 0.f ? v1 : 0.2f * v1;
            p1 = att1 * v1;
        }
#pragma unroll
        for (int m = 32; m; m >>= 1) {
            p0 += __shfl_xor(p0, m);
            if constexpr (H == 2) p1 += __shfl_xor(p1, m);
        }
        float ex0 = __expf(p0);
        acc0 = fmaf(ex0, xl0, acc0);
        den0 += ex0;
        if constexpr (H == 2) {
            float ex1 = __expf(p1);
            acc1 = fmaf(ex1, xl1, acc1);
            den1 += ex1;
        }
    }
    float o0 = acc0 / (den0 + 1e-16f) + b0;
    if (RELU) o0 = o0 > 0.f ? o0 : 0.f;
    out[(size_t)n * HC + lane] = o0;
    if constexpr (H == 2) {
        float o1 = acc1 / (den1 + 1e-16f) + b1;
        if (RELU) o1 = o1 > 0.f ? o1 : 0.f;
        out[(size_t)n * HC + 64 + lane] = o1;
    }
}

// ---------------- gate MLP ----------------
__global__ __launch_bounds__(256) void k_gate(const float* __restrict__ h, const float* __restrict__ G1w,
                                              const float* __restrict__ G1b, const float* __restrict__ G2w,
                                              const float* __restrict__ G2b,
                                              float* __restrict__ gate, int N) {
    __shared__ float sH[64][64];
    __shared__ float part[64][2];
    int t = threadIdx.x;
    int n0 = blockIdx.x * 64;
    for (int l = t; l < 1024; l += 256) {
        float4 v = ((const float4*)(h + (size_t)n0 * 64))[l];
        int n = l >> 4, kq = (l & 15) << 2;
        *(float4*)&sH[n][kq] = v;
    }
    int c = t & 127, half = t >> 7;
    float rW[64];
#pragma unroll
    for (int k = 0; k < 64; k++) rW[k] = G1w[k * 128 + c];
    float g1b = G1b[c], g2w = G2w[c];
    __syncthreads();
    for (int nn = 0; nn < 32; nn++) {
        int n = half * 32 + nn;
        float acc = g1b;
#pragma unroll
        for (int k = 0; k < 64; k += 4) {
            float4 hv = *(const float4*)&sH[n][k];
            acc = fmaf(hv.x, rW[k], acc);
            acc = fmaf(hv.y, rW[k + 1], acc);
            acc = fmaf(hv.z, rW[k + 2], acc);
            acc = fmaf(hv.w, rW[k + 3], acc);
        }
        acc = acc > 0.f ? acc : 0.f;
        float p = acc * g2w;
#pragma unroll
        for (int m = 32; m; m >>= 1) p += __shfl_xor(p, m);
        if ((t & 63) == 0) part[n][(t >> 6) & 1] = p;
    }
    __syncthreads();
    if (t < 64) gate[n0 + t] = __expf(part[t][0] + part[t][1] + G2b[0]);
}

// ---------------- pooling ----------------
__global__ __launch_bounds__(256) void k_pool(const float* __restrict__ h, const float* __restrict__ gate,
                                              const int* __restrict__ batch,
                                              float* __restrict__ pooled, int N) {
    int g = blockIdx.x;
    int lo = 0, hi = N;
    while (lo < hi) { int mid = (lo + hi) >> 1; if (batch[mid] < g) lo = mid + 1; else hi = mid; }
    int start = lo;
    lo = 0; hi = N;
    while (lo < hi) { int mid = (lo + hi) >> 1; if (batch[mid] < g + 1) lo = mid + 1; else hi = mid; }
    int end = lo;
    int t = threadIdx.x, wv = t >> 6, lane = t & 63;
    float acc = 0.f, den = 0.f;
    for (int n = start + wv; n < end; n += 4) {
        float gv = gate[n];
        acc = fmaf(gv, h[(size_t)n * 64 + lane], acc);
        den += gv;
    }
    __shared__ float sacc[4][64];
    __shared__ float sden[4];
    sacc[wv][lane] = acc;
    if (lane == 0) sden[wv] = den;
    __syncthreads();
    if (wv == 0) {
        float a = sacc[0][lane] + sacc[1][lane] + sacc[2][lane] + sacc[3][lane];
        float d = sden[0] + sden[1] + sden[2] + sden[3] + 1e-16f;
        pooled[g * 64 + lane] = a / d;
    }
}

__global__ void k_final(const float* __restrict__ pooled, const float* __restrict__ Wreg,
                        const float* __restrict__ breg, float* __restrict__ out) {
    int g = threadIdx.x;
    float acc = breg[0];
    for (int c = 0; c < 64; c++) acc += pooled[g * 64 + c] * Wreg[c];
    out[g] = acc;
}

extern "C" void kernel_launch(void* const* d_in, const int* in_sizes, int n_in,
                              void* d_out, int out_size, void* d_ws, size_t ws_size,
                              hipStream_t stream) {
    const float* x  = (const float*)d_in[0];
    const float* ea = (const float*)d_in[1];
    const int* ei    = (const int*)d_in[2];
    const int* batch = (const int*)d_in[3];
    auto ff = [&](int i) { return (const float*)d_in[i]; };
    const float *W1l = ff(4), *b1l = ff(5), *W1r = ff(6), *b1r = ff(7), *W1e = ff(8),
                *att1 = ff(9), *bias1 = ff(10);
    const float *W2l = ff(11), *b2l = ff(12), *W2r = ff(13), *b2r = ff(14), *W2e = ff(15),
                *att2 = ff(16), *bias2 = ff(17);
    const float *W3l = ff(18), *b3l = ff(19), *W3r = ff(20), *b3r = ff(21), *W3e = ff(22),
                *att3 = ff(23), *bias3 = ff(24);
    const float *G1w = ff(25), *G1b = ff(26), *G2w = ff(27), *G2b = ff(28), *Wreg = ff(29),
                *breg = ff(30);

    const int N = in_sizes[0] / 128;  // 40000
    const int E = in_sizes[2] / 2;    // 640000

    char* ws = (char*)d_ws;
    float*  bufA    = (float*)(ws);              // [N,128]
    float*  bufB    = (float*)(ws + 20480000);   // [N,128]
    float*  bufH    = (float*)(ws + 40960000);   // [N,128]
    int*    esrc    = (int*)(ws + 61440000);     // [E]
    int*    eeid    = (int*)(ws + 64000000);     // [E]
    int*    row_ptr = (int*)(ws + 66560000);     // [N]
    int*    deg     = (int*)(ws + 66720000);     // [N]
    int*    cursor  = (int*)(ws + 66880000);     // [N]
    int*    excl    = (int*)(ws + 67040000);     // [N]
    int*    parts   = (int*)(ws + 67200000);     // [<=256]
    float*  gate    = (float*)(ws + 67204096);   // [N]
    float*  pooled  = (float*)(ws + 67364096);   // [64,64]
    int*    edst    = (int*)(ws + 67380480);     // [E]
    float*  logit   = (float*)(ws + 69940480);   // [E,2]
    const bool newpath = ws_size >= (size_t)69940480 + (size_t)E * 2 * 4;

    auto cdiv = [](int a, int b) { return (a + b - 1) / b; };
    const int NB = cdiv(N, 256);
    const dim3 gemmG(N / 64, 2);
    const int ELB = cdiv(E, 64);
    const int AGB = cdiv(N, 2);

    // ---- CSR build (once; graph shared by all 3 layers) ----
    k_fill<<<NB, 256, 0, stream>>>((unsigned*)deg, N, 0u);
    k_hist<<<cdiv(E, 256), 256, 0, stream>>>(ei, E, deg);
    k_scan_blocks<<<NB, 256, 0, stream>>>(deg, N, excl, parts);
    k_scan_parts<<<1, 256, 0, stream>>>(parts, NB);
    k_scan_add<<<NB, 256, 0, stream>>>(excl, parts, row_ptr, cursor, N);
    k_scatter<<<cdiv(E, 256), 256, 0, stream>>>(ei, E, cursor, esrc, eeid);

    if (newpath) {
        k_dstfill<<<NB, 256, 0, stream>>>(row_ptr, deg, edst, N);
        // ---- layer 1 ----
        k_gemm2<128, 8><<<gemmG, 256, 0, stream>>>(x, W1l, b1l, W1r, b1r, bufA, bufB);
        k_elogit<128><<<ELB, 256, 0, stream>>>(ea, eeid, esrc, edst, W1e, att1, bufA, bufB, logit, E);
        k_aggv<2, true><<<AGB, 256, 0, stream>>>(bufA, logit, esrc, row_ptr, deg, bias1, bufH, N);
        // ---- layer 2 ----
        k_gemm2<128, 8><<<gemmG, 256, 0, stream>>>(bufH, W2l, b2l, W2r, b2r, bufA, bufB);
        k_elogit<128><<<ELB, 256, 0, stream>>>(ea, eeid, esrc, edst, W2e, att2, bufA, bufB, logit, E);
        k_aggv<2, true><<<AGB, 256, 0, stream>>>(bufA, logit, esrc, row_ptr, deg, bias2, bufH, N);
        // ---- layer 3 ----
        k_gemm2<64, 4><<<gemmG, 256, 0, stream>>>(bufH, W3l, b3l, W3r, b3r, bufA, bufB);
        k_elogit<64><<<ELB, 256, 0, stream>>>(ea, eeid, esrc, edst, W3e, att3, bufA, bufB, logit, E);
        k_aggv<1, false><<<AGB, 256, 0, stream>>>(bufA, logit, esrc, row_ptr, deg, bias3, bufH, N);
    } else {
        const int AGGB = cdiv(N, 4);
        k_gemm2<128, 8><<<gemmG, 256, 0, stream>>>(x, W1l, b1l, W1r, b1r, bufA, bufB);
        k_agg_fb<2, true><<<AGGB, 256, 0, stream>>>(bufA, bufB, ea, esrc, eeid, row_ptr, deg, W1e, att1, bias1, bufH, N);
        k_gemm2<128, 8><<<gemmG, 256, 0, stream>>>(bufH, W2l, b2l, W2r, b2r, bufA, bufB);
        k_agg_fb<2, true><<<AGGB, 256, 0, stream>>>(bufA, bufB, ea, esrc, eeid, row_ptr, deg, W2e, att2, bias2, bufH, N);
        k_gemm2<64, 4><<<gemmG, 256, 0, stream>>>(bufH, W3l, b3l, W3r, b3r, bufA, bufB);
        k_agg_fb<1, false><<<AGGB, 256, 0, stream>>>(bufA, bufB, ea, esrc, eeid, row_ptr, deg, W3e, att3, bias3, bufH, N);
    }

    // ---- attentional pooling + regressor ----
    k_gate<<<N / 64, 256, 0, stream>>>(bufH, G1w, G1b, G2w, G2b, gate, N);
    k_pool<<<64, 256, 0, stream>>>(bufH, gate, batch, pooled, N);
    k_final<<<1, 64, 0, stream>>>(pooled, Wreg, breg, (float*)d_out);
}